// Round 11
// baseline (266.285 us; speedup 1.0000x reference)
//
#include <hip/hip_runtime.h>
#include <hip/hip_bf16.h>
#include <stdint.h>

#define L_SEQ 2048
#define S_SEQ 2048
#define BATCH 2
#define EMB 1024
#define NH 16
#define HD 64
#define MROWS 4096  // L*B == S*B

typedef __bf16 bf16x8 __attribute__((ext_vector_type(8)));
typedef float f32x4 __attribute__((ext_vector_type(4)));
typedef __hip_bfloat16 bf16;

__device__ __forceinline__ f32x4 mfma16(bf16x8 a, bf16x8 b, f32x4 c) {
    return __builtin_amdgcn_mfma_f32_16x16x32_bf16(a, b, c, 0, 0, 0);
}

// async global->LDS, 16B per lane. LDS dest = wave-uniform base + lane*16.
__device__ __forceinline__ void gll16(const bf16* g, bf16* l) {
    __builtin_amdgcn_global_load_lds(
        (const __attribute__((address_space(1))) void*)g,
        (__attribute__((address_space(3))) void*)l, 16, 0, 0);
}
__device__ __forceinline__ void gllf(const float* g, float* l) {
    __builtin_amdgcn_global_load_lds(
        (const __attribute__((address_space(1))) void*)g,
        (__attribute__((address_space(3))) void*)l, 16, 0, 0);
}

// load 8 consecutive fp32, round to bf16, pack into one 16B fragment
__device__ __forceinline__ bf16x8 ld8_cvt(const float* p) {
    const float4 a = *reinterpret_cast<const float4*>(p);
    const float4 b = *reinterpret_cast<const float4*>(p + 4);
    union { bf16x8 v; bf16 h[8]; } u;
    u.h[0] = __float2bfloat16(a.x); u.h[1] = __float2bfloat16(a.y);
    u.h[2] = __float2bfloat16(a.z); u.h[3] = __float2bfloat16(a.w);
    u.h[4] = __float2bfloat16(b.x); u.h[5] = __float2bfloat16(b.y);
    u.h[6] = __float2bfloat16(b.z); u.h[7] = __float2bfloat16(b.w);
    return u.v;
}

// fast pack: two f32 -> bf16x2 via +0x8000 round bias and v_perm_b32 (3 insts)
// NOTE (round-9 lesson): v_cvt_pk_bf16_f32 inline asm produced a pair-swapped
// P layout (absmax 5e-2). packbf2 is the verified path — do not swap back.
__device__ __forceinline__ uint32_t packbf2(float a, float b) {
    const uint32_t ra = __float_as_uint(a) + 0x8000u;
    const uint32_t rb = __float_as_uint(b) + 0x8000u;
    return __builtin_amdgcn_perm(rb, ra, 0x07060302u);  // [rb.b3 rb.b2 ra.b3 ra.b2]
}

// 8 fp32 (two float4) -> bf16x8 fragment
__device__ __forceinline__ bf16x8 pack8(float4 lo, float4 hi) {
    union { uint32_t u[4]; bf16x8 v; } t;
    t.u[0] = packbf2(lo.x, lo.y); t.u[1] = packbf2(lo.z, lo.w);
    t.u[2] = packbf2(hi.x, hi.y); t.u[3] = packbf2(hi.z, hi.w);
    return t.v;
}

// QK^T C-layout -> PV A-fragment lane redistribution, in-register (verified r3)
__device__ __forceinline__ bf16x8 pfrag(const uint32_t* pk0, const uint32_t* pk1, int sk) {
    auto t0 = __builtin_amdgcn_permlane32_swap(pk0[2 * sk], pk0[2 * sk + 1], false, false);
    auto a02 = __builtin_amdgcn_permlane16_swap(t0[0], t0[1], false, false);
    auto t1 = __builtin_amdgcn_permlane32_swap(pk1[2 * sk], pk1[2 * sk + 1], false, false);
    auto a13 = __builtin_amdgcn_permlane16_swap(t1[0], t1[1], false, false);
    union { uint32_t u[4]; bf16x8 v; } pf;
    pf.u[0] = a02[0]; pf.u[1] = a13[0]; pf.u[2] = a02[1]; pf.u[3] = a13[1];
    return pf.v;
}

// ---------------------------------------------------------------------------
// fp32 -> bf16 for the WEIGHTS only (w_in 3M + w_out 1M elems = 24 MB traffic).
// q/k/v are consumed as raw fp32 by qkv_gemm (round 11).
// ---------------------------------------------------------------------------
__global__ __launch_bounds__(256) void cvt_kernel(
    const float* __restrict__ w_in, const float* __restrict__ w_out,
    bf16* __restrict__ wib, bf16* __restrict__ wob)
{
    const size_t i = ((size_t)blockIdx.x * 256 + threadIdx.x) * 8;
    const size_t o1 = (size_t)3 * EMB * EMB;        // 3,145,728
    if (i < o1) *reinterpret_cast<bf16x8*>(wib + i) = ld8_cvt(w_in + i);
    else        *reinterpret_cast<bf16x8*>(wob + (i - o1)) = ld8_cvt(w_out + (i - o1));
}

// ---------------------------------------------------------------------------
// Fused QKV projection, 2-phase double-buffered GLL staging.
// Round 11: A-operand is the RAW FP32 input (query/key/value) staged via
// global_load_lds into an fp32 LDS tile (128x32 fp32, 4 issues/buffer) with
// the (row&7) XOR chunk-swizzle applied on the per-lane SOURCE address
// (m173 pattern; fp32 rows = 128 B = 8 chunks -> full-spread, conflict-free
// fragment reads). Conversion to bf16 happens at fragment-load (packbf2).
// B stays bf16 (wib). Deletes 72 MB of cvt traffic.
// Epilogue: Qh[bh][l][d] (x0.125*log2e), Kh[bh][s][d], Vt[bh][d][s].
// ---------------------------------------------------------------------------
__global__ __launch_bounds__(256) void qkv_gemm(
    const float* __restrict__ Xq, const float* __restrict__ Xk,
    const float* __restrict__ Xv, const bf16* __restrict__ wib,
    const float* __restrict__ b_in,
    bf16* __restrict__ Qh, bf16* __restrict__ Kh, bf16* __restrict__ Vt)
{
    __shared__ alignas(16) float lds_a[2][128 * 32];   // fp32 A, chunk^row swizzled
    __shared__ alignas(16) bf16  lds_b[2][128 * 32];   // bf16 B, linear

    const int tid  = threadIdx.x;
    const int lane = tid & 63;
    const int wv   = tid >> 6;
    const int quad = lane >> 4;
    const int lx   = lane & 15;
    const int lx7  = lane & 7;

    const int m0  = blockIdx.x * 128;
    const int n0g = blockIdx.y * 128;
    const int chunk = n0g >> 10;              // 0=Q, 1=K, 2=V
    const float* Aop = (chunk == 0) ? Xq : (chunk == 1) ? Xk : Xv;

    const int wm = (wv >> 1) * 64;
    const int wn = (wv & 1) * 64;

    // A staging (fp32): thread covers row arow+32*i, LDS 16B-chunk tid&7;
    // source chunk pre-swizzled: LDS[r][p] = A[r][(p ^ (r&7))*4 ..]
    const int arow = tid >> 3;                       // 0..31
    const int acs  = ((tid & 7) ^ (arow & 7)) * 4;   // swizzled source col (floats)
    const float* gA = Aop + (size_t)(m0 + arow) * EMB + acs;

    // B staging (bf16): wave wv, issue i covers rows 16*wv + 64*i + (lane>>2)
    const int gr = 16 * wv + (lane >> 2);
    const int gc = (lane & 3) * 8;
    const bf16* gB = wib + (size_t)(n0g + gr) * EMB + gc;

    f32x4 acc[4][4];
#pragma unroll
    for (int i = 0; i < 4; i++)
#pragma unroll
        for (int j = 0; j < 4; j++) acc[i][j] = (f32x4){0.f, 0.f, 0.f, 0.f};

    // prologue: stage kt=0 into buf 0
#pragma unroll
    for (int i = 0; i < 4; i++)
        gllf(gA + (size_t)(i * 32) * EMB, &lds_a[0][i * 1024 + wv * 256]);
    gll16(gB, &lds_b[0][wv * 512]);
    gll16(gB + 64 * EMB, &lds_b[0][wv * 512 + 2048]);
    __syncthreads();   // vmcnt(0) drain: buf 0 ready

    int cur = 0;
    for (int kt = 0; kt < EMB; kt += 32) {
        // prefetch next K-slab into the other buffer (overlaps this compute)
        if (kt + 32 < EMB) {
            const int nx = cur ^ 1;
#pragma unroll
            for (int i = 0; i < 4; i++)
                gllf(gA + (size_t)(i * 32) * EMB + kt + 32, &lds_a[nx][i * 1024 + wv * 256]);
            gll16(gB + kt + 32, &lds_b[nx][wv * 512]);
            gll16(gB + 64 * EMB + kt + 32, &lds_b[nx][wv * 512 + 2048]);
        }

        bf16x8 af[4], bfv[4];
        const int ka = quad * 8;
        const float* pa = &lds_a[cur][0];
        const bf16*  pb = &lds_b[cur][0];
#pragma unroll
        for (int sm = 0; sm < 4; sm++) {
            const float* pr = pa + (wm + sm * 16 + lx) * 32;   // row&7 == lx7
            const float4 lo = *reinterpret_cast<const float4*>(pr + (((2 * quad)     ^ lx7) * 4));
            const float4 hi = *reinterpret_cast<const float4*>(pr + (((2 * quad + 1) ^ lx7) * 4));
            af[sm] = pack8(lo, hi);
        }
#pragma unroll
        for (int sn = 0; sn < 4; sn++)
            bfv[sn] = *reinterpret_cast<const bf16x8*>(pb + (wn + sn * 16 + lx) * 32 + ka);
#pragma unroll
        for (int sm = 0; sm < 4; sm++)
#pragma unroll
            for (int sn = 0; sn < 4; sn++)
                acc[sm][sn] = mfma16(af[sm], bfv[sn], acc[sm][sn]);

        if (kt + 32 < EMB) __syncthreads();  // prefetch landed + buf[cur] free
        cur ^= 1;
    }

    const float scale = (chunk == 0) ? 0.18033688011112042f : 1.0f;
    bf16* dst = (chunk == 0) ? Qh : (chunk == 1) ? Kh : Vt;
#pragma unroll
    for (int sn = 0; sn < 4; sn++) {
        const int n_g = n0g + wn + sn * 16 + lx;
        const float bias = b_in[n_g];
        const int nc = n_g & (EMB - 1);
        const int h  = nc >> 6;
        const int dd = nc & 63;
#pragma unroll
        for (int sm = 0; sm < 4; sm++) {
#pragma unroll
            for (int r = 0; r < 4; r++) {
                const int m_g = m0 + wm + sm * 16 + quad * 4 + r;  // row = l*B + b
                const int t = m_g >> 1;
                const int b = m_g & 1;
                const int bhidx = b * NH + h;
                const float v = (acc[sm][sn][r] + bias) * scale;
                const size_t off = (chunk == 2)
                    ? ((size_t)bhidx * HD + dd) * S_SEQ + t     // V transposed
                    : ((size_t)bhidx * S_SEQ + t) * HD + dd;    // Q, K row-major
                dst[off] = __float2bfloat16(v);
            }
        }
    }
}

// ---------------------------------------------------------------------------
// Flash attention: no-max log2-domain softmax, q=32/wave, K+V via
// global_load_lds pre-swizzled, double-buffered 64 KiB. (unchanged, verified)
// ---------------------------------------------------------------------------
__global__ __launch_bounds__(256, 2) void attn_kernel(
    const bf16* __restrict__ Qh, const bf16* __restrict__ Kh,
    const bf16* __restrict__ Vt, bf16* __restrict__ ctx)
{
    __shared__ alignas(16) bf16 k_lds[2][128 * 64];  // [s][d], col^row swizzled
    __shared__ alignas(16) bf16 v_lds[2][64 * 128];  // [d][s], chunk^d swizzled

    const int tid  = threadIdx.x;
    const int lane = tid & 63;
    const int wv   = tid >> 6;      // 0..3
    const int quad = lane >> 4;
    const int lx   = lane & 15;
    const int lx7  = lane & 7;

    const int bh = blockIdx.y;
    const int l0 = blockIdx.x * 128;
    const int q0 = wv * 32;

    const bf16* Kbase = Kh + (size_t)bh * S_SEQ * HD;
    const bf16* Vbase = Vt + (size_t)bh * HD * S_SEQ;

    // Q as B-operand, two 16-q groups (a: rows q0.., b: rows q0+16..)
    const bf16* qrow = Qh + ((size_t)bh * L_SEQ + l0 + q0 + lx) * HD + quad * 8;
    const bf16x8 qa0 = *reinterpret_cast<const bf16x8*>(qrow);
    const bf16x8 qa1 = *reinterpret_cast<const bf16x8*>(qrow + 32);
    const bf16x8 qb0 = *reinterpret_cast<const bf16x8*>(qrow + 16 * HD);
    const bf16x8 qb1 = *reinterpret_cast<const bf16x8*>(qrow + 16 * HD + 32);

    f32x4 rva = (f32x4){0.f, 0.f, 0.f, 0.f};   // per-lane partial l sums
    f32x4 rvb = (f32x4){0.f, 0.f, 0.f, 0.f};
    f32x4 acca[4], accb[4];
#pragma unroll
    for (int sn = 0; sn < 4; sn++) {
        acca[sn] = (f32x4){0.f, 0.f, 0.f, 0.f};
        accb[sn] = (f32x4){0.f, 0.f, 0.f, 0.f};
    }

    // K staging: LDS row kr = tid>>3 (+32 per issue), chunk kj = tid&7;
    // source col pre-swizzled: LDS[r][j] = K[s0+r][(j ^ (r&7))*8..]
    const int kr = tid >> 3;
    const int kj = tid & 7;
    const bf16* gK = Kbase + (size_t)kr * HD + ((kj ^ (kr & 7)) << 3);
    // V staging: LDS d-row vd = tid>>4 (+16 per issue), chunk vj = tid&15;
    // LDS[d][j] = V[d][s0 + (j ^ (d&7))*8..]
    const int vd = tid >> 4;
    const int vj = tid & 15;
    const bf16* gV = Vbase + (size_t)vd * S_SEQ + ((vj ^ (vd & 7)) << 3);

    // wave-uniform LDS dest bases (elems); each issue covers +2048 elems
    bf16* kdst[2] = { &k_lds[0][wv * 512], &k_lds[1][wv * 512] };
    bf16* vdst[2] = { &v_lds[0][wv * 512], &v_lds[1][wv * 512] };

    // prologue: stage tile 0 into buf 0
#pragma unroll
    for (int i = 0; i < 4; i++) {
        gll16(gK + (size_t)(i * 32) * HD, kdst[0] + i * 2048);
        gll16(gV + (size_t)(i * 16) * S_SEQ, vdst[0] + i * 2048);
    }

    int cur = 0;
    for (int s0 = 0; s0 < S_SEQ; s0 += 128) {
        __syncthreads();   // vmcnt(0)+barrier: buf[cur] DMA complete, safe reuse

        if (s0 + 128 < S_SEQ) {
            bf16* kd = kdst[cur ^ 1];
            bf16* vdp = vdst[cur ^ 1];
#pragma unroll
            for (int i = 0; i < 4; i++) {
                gll16(gK + (size_t)(s0 + 128 + i * 32) * HD, kd + i * 2048);
                gll16(gV + (size_t)(i * 16) * S_SEQ + s0 + 128, vdp + i * 2048);
            }
        }
        const bf16* kb = &k_lds[cur][0];
        const bf16* vb = &v_lds[cur][0];

        // QK^T both groups: one K-frag read feeds 4 mfmas
        f32x4 sa[8], sb[8];
#pragma unroll
        for (int c = 0; c < 8; c++) {
            const bf16* krp = kb + (c * 16 + lx) * 64;
            bf16x8 kf0 = *reinterpret_cast<const bf16x8*>(krp + ((quad ^ lx7) << 3));
            bf16x8 kf1 = *reinterpret_cast<const bf16x8*>(krp + (((quad + 4) ^ lx7) << 3));
            f32x4 t0 = (f32x4){0.f, 0.f, 0.f, 0.f};
            t0 = mfma16(kf0, qa0, t0);
            t0 = mfma16(kf1, qa1, t0);
            sa[c] = t0;
            f32x4 t1 = (f32x4){0.f, 0.f, 0.f, 0.f};
            t1 = mfma16(kf0, qb0, t1);
            t1 = mfma16(kf1, qb1, t1);
            sb[c] = t1;
        }

        // P = exp2(s) directly (no max); accumulate l per-lane; pack for PV.
        uint32_t pka0[8], pka1[8], pkb0[8], pkb1[8];
#pragma unroll
        for (int c = 0; c < 8; c++) {
#pragma unroll
            for (int r = 0; r < 4; r++) sa[c][r] = __builtin_amdgcn_exp2f(sa[c][r]);
            rva += sa[c];
            pka0[c] = packbf2(sa[c][0], sa[c][1]);
            pka1[c] = packbf2(sa[c][2], sa[c][3]);
        }
#pragma unroll
        for (int c = 0; c < 8; c++) {
#pragma unroll
            for (int r = 0; r < 4; r++) sb[c][r] = __builtin_amdgcn_exp2f(sb[c][r]);
            rvb += sb[c];
            pkb0[c] = packbf2(sb[c][0], sb[c][1]);
            pkb1[c] = packbf2(sb[c][2], sb[c][3]);
        }

        // PV: each V-frag read feeds both groups' mfmas
#pragma unroll
        for (int sk = 0; sk < 4; sk++) {
            const bf16x8 pfa = pfrag(pka0, pka1, sk);
            const bf16x8 pfb = pfrag(pkb0, pkb1, sk);
#pragma unroll
            for (int sn = 0; sn < 4; sn++) {
                const bf16x8 vf = *reinterpret_cast<const bf16x8*>(
                    vb + (sn * 16 + lx) * 128 + (((sk * 4 + quad) ^ lx7) << 3));
                acca[sn] = mfma16(pfa, vf, acca[sn]);
                accb[sn] = mfma16(pfb, vf, accb[sn]);
            }
        }
        cur ^= 1;
    }

    // epilogue: single cross-lane l reduce
    float la = (rva[0] + rva[1]) + (rva[2] + rva[3]);
    la += __shfl_xor(la, 16);
    la += __shfl_xor(la, 32);
    float lbs = (rvb[0] + rvb[1]) + (rvb[2] + rvb[3]);
    lbs += __shfl_xor(lbs, 16);
    lbs += __shfl_xor(lbs, 32);

    const int b = bh >> 4;
    const int h = bh & 15;
#pragma unroll
    for (int r = 0; r < 4; r++) {
        const float lra = __shfl(la, quad * 20 + r);
        const float lrb = __shfl(lbs, quad * 20 + r);
        const float inva = 1.f / lra;
        const float invb = 1.f / lrb;
        const int lA = l0 + q0 + quad * 4 + r;
        const int lB = lA + 16;
#pragma unroll
        for (int sn = 0; sn < 4; sn++) {
            const int dd = sn * 16 + lx;
            ctx[(size_t)(lA * BATCH + b) * EMB + h * HD + dd] =
                __float2bfloat16(acca[sn][r] * inva);
            ctx[(size_t)(lB * BATCH + b) * EMB + h * HD + dd] =
                __float2bfloat16(accb[sn][r] * invb);
        }
    }
}

// ---------------------------------------------------------------------------
// Output projection: 64x128 tile -> 512 blocks (2/CU), 2-phase double-buffered
// GLL staging. LDS 24 KiB. fp32 out. (unchanged)
// ---------------------------------------------------------------------------
__global__ __launch_bounds__(256) void out_gemm(
    const bf16* __restrict__ ctx, const bf16* __restrict__ wob,
    const float* __restrict__ b_out, float* __restrict__ out)
{
    __shared__ alignas(16) bf16 lds_a[2][64 * 32];
    __shared__ alignas(16) bf16 lds_b[2][128 * 32];

    const int tid  = threadIdx.x;
    const int lane = tid & 63;
    const int wv   = tid >> 6;
    const int quad = lane >> 4;
    const int lx   = lane & 15;

    const int m0 = blockIdx.x * 64;
    const int n0 = blockIdx.y * 128;

    const int wm = (wv >> 1) * 32;
    const int wn = (wv & 1) * 64;

    const int gr = 16 * wv + (lane >> 2);
    const int gc = (lane & 3) * 8;
    const bf16* gA = ctx + (size_t)(m0 + gr) * EMB + gc;   // rows 0..63
    const bf16* gB = wob + (size_t)(n0 + gr) * EMB + gc;   // rows 0..63 (+64)
    bf16* lA = &lds_a[0][wv * 512];
    bf16* lB = &lds_b[0][wv * 512];
    const int BUFA = 64 * 32;
    const int BUFB = 128 * 32;

    f32x4 acc[2][4];
#pragma unroll
    for (int i = 0; i < 2; i++)
#pragma unroll
        for (int j = 0; j < 4; j++) acc[i][j] = (f32x4){0.f, 0.f, 0.f, 0.f};

    // prologue: stage kt=0 into buf 0
    gll16(gA, lA);
    gll16(gB, lB);
    gll16(gB + 64 * EMB, lB + 2048);
    __syncthreads();

    int cur = 0;
    for (int kt = 0; kt < EMB; kt += 32) {
        if (kt + 32 < EMB) {
            const int nx = cur ^ 1;
            gll16(gA + kt + 32, lA + nx * BUFA);
            gll16(gB + kt + 32, lB + nx * BUFB);
            gll16(gB + 64 * EMB + kt + 32, lB + nx * BUFB + 2048);
        }

        bf16x8 af[2], bfv[4];
        const int ka = quad * 8;
        const bf16* pa = &lds_a[cur][0];
        const bf16* pb = &lds_b[cur][0];
#pragma unroll
        for (int sm = 0; sm < 2; sm++)
            af[sm] = *reinterpret_cast<const bf16x8*>(pa + (wm + sm * 16 + lx) * 32 + ka);
#pragma unroll
        for (int sn = 0; sn < 4; sn++)
            bfv[sn] = *reinterpret_cast<const bf16x8*>(pb + (wn + sn * 16 + lx) * 32 + ka);
#pragma unroll
        for (int sm = 0; sm < 2; sm++)
#pragma unroll
            for (int sn = 0; sn < 4; sn++)
                acc[sm][sn] = mfma16(af[sm], bfv[sn], acc[sm][sn]);

        if (kt + 32 < EMB) __syncthreads();
        cur ^= 1;
    }

#pragma unroll
    for (int sn = 0; sn < 4; sn++) {
        const int n_g = n0 + wn + sn * 16 + lx;
        const float bias = b_out[n_g];
#pragma unroll
        for (int sm = 0; sm < 2; sm++) {
#pragma unroll
            for (int r = 0; r < 4; r++) {
                const int m_g = m0 + wm + sm * 16 + quad * 4 + r;
                out[(size_t)m_g * EMB + n_g] = acc[sm][sn][r] + bias;
            }
        }
    }
}

extern "C" void kernel_launch(void* const* d_in, const int* in_sizes, int n_in,
                              void* d_out, int out_size, void* d_ws, size_t ws_size,
                              hipStream_t stream)
{
    const float* query = (const float*)d_in[0];
    const float* key_  = (const float*)d_in[1];
    const float* value = (const float*)d_in[2];
    const float* w_in  = (const float*)d_in[3];
    const float* b_in  = (const float*)d_in[4];
    const float* w_out = (const float*)d_in[5];
    const float* b_out = (const float*)d_in[6];
    float* out = (float*)d_out;

    const size_t seg = (size_t)MROWS * EMB;      // 4,194,304 elems (8 MiB bf16)
    bf16* wib = (bf16*)d_ws;                     // 3*EMB*EMB
    bf16* wob = wib + (size_t)3 * EMB * EMB;     // EMB*EMB
    bf16* Qh  = wob + (size_t)EMB * EMB;         // [bh][l][d], scaled log2e/8
    bf16* Kh  = Qh + seg;                        // [bh][s][d]
    bf16* Vt  = Kh + seg;                        // [bh][d][s] — written by qkv_gemm
    bf16* ctx = Vt + seg;                        // [l*B+b][E]

    cvt_kernel<<<2048, 256, 0, stream>>>(w_in, w_out, wib, wob);
    qkv_gemm<<<dim3(32, 24), 256, 0, stream>>>(query, key_, value, wib, b_in, Qh, Kh, Vt);
    attn_kernel<<<dim3(16, 32), 256, 0, stream>>>(Qh, Kh, Vt, ctx);
    out_gemm<<<dim3(64, 8), 256, 0, stream>>>(ctx, wob, b_out, out);
}

// Round 12
// 217.154 us; speedup vs baseline: 1.2262x; 1.2262x over previous
//
#include <hip/hip_runtime.h>
#include <hip/hip_bf16.h>
#include <stdint.h>

#define L_SEQ 2048
#define S_SEQ 2048
#define BATCH 2
#define EMB 1024
#define NH 16
#define HD 64
#define MROWS 4096  // L*B == S*B

typedef __bf16 bf16x8 __attribute__((ext_vector_type(8)));
typedef float f32x4 __attribute__((ext_vector_type(4)));
typedef __hip_bfloat16 bf16;

__device__ __forceinline__ f32x4 mfma16(bf16x8 a, bf16x8 b, f32x4 c) {
    return __builtin_amdgcn_mfma_f32_16x16x32_bf16(a, b, c, 0, 0, 0);
}

// async global->LDS, 16B per lane. LDS dest = wave-uniform base + lane*16.
__device__ __forceinline__ void gll16(const bf16* g, bf16* l) {
    __builtin_amdgcn_global_load_lds(
        (const __attribute__((address_space(1))) void*)g,
        (__attribute__((address_space(3))) void*)l, 16, 0, 0);
}

// load 8 consecutive fp32, round to bf16, pack into one 16B fragment
__device__ __forceinline__ bf16x8 ld8_cvt(const float* p) {
    const float4 a = *reinterpret_cast<const float4*>(p);
    const float4 b = *reinterpret_cast<const float4*>(p + 4);
    union { bf16x8 v; bf16 h[8]; } u;
    u.h[0] = __float2bfloat16(a.x); u.h[1] = __float2bfloat16(a.y);
    u.h[2] = __float2bfloat16(a.z); u.h[3] = __float2bfloat16(a.w);
    u.h[4] = __float2bfloat16(b.x); u.h[5] = __float2bfloat16(b.y);
    u.h[6] = __float2bfloat16(b.z); u.h[7] = __float2bfloat16(b.w);
    return u.v;
}

// fast pack: two f32 -> bf16x2 via +0x8000 round bias and v_perm_b32 (3 insts)
// NOTE (round-9 lesson): v_cvt_pk_bf16_f32 inline asm produced a pair-swapped
// P layout (absmax 5e-2). packbf2 is the verified path — do not swap back.
// NOTE (round-11 lesson): staging A as fp32 in LDS (to skip the cvt pass) is
// a net loss: 2x LDS bytes on the fragment path, fp32 rows = 128 B alias all
// 32 banks (conflicts UP), + pack VALU on the critical path. Keep bf16 LDS.
__device__ __forceinline__ uint32_t packbf2(float a, float b) {
    const uint32_t ra = __float_as_uint(a) + 0x8000u;
    const uint32_t rb = __float_as_uint(b) + 0x8000u;
    return __builtin_amdgcn_perm(rb, ra, 0x07060302u);  // [rb.b3 rb.b2 ra.b3 ra.b2]
}

// QK^T C-layout -> PV A-fragment lane redistribution, in-register (verified r3)
__device__ __forceinline__ bf16x8 pfrag(const uint32_t* pk0, const uint32_t* pk1, int sk) {
    auto t0 = __builtin_amdgcn_permlane32_swap(pk0[2 * sk], pk0[2 * sk + 1], false, false);
    auto a02 = __builtin_amdgcn_permlane16_swap(t0[0], t0[1], false, false);
    auto t1 = __builtin_amdgcn_permlane32_swap(pk1[2 * sk], pk1[2 * sk + 1], false, false);
    auto a13 = __builtin_amdgcn_permlane16_swap(t1[0], t1[1], false, false);
    union { uint32_t u[4]; bf16x8 v; } pf;
    pf.u[0] = a02[0]; pf.u[1] = a13[0]; pf.u[2] = a02[1]; pf.u[3] = a13[1];
    return pf.v;
}

// ---------------------------------------------------------------------------
// fp32 -> bf16 for w_in, w_out, q, k, v (one memory-bound pass; GEMMs use GLL).
// ---------------------------------------------------------------------------
__global__ __launch_bounds__(256) void cvt_kernel(
    const float* __restrict__ w_in, const float* __restrict__ w_out,
    const float* __restrict__ q_in, const float* __restrict__ k_in,
    const float* __restrict__ v_in,
    bf16* __restrict__ wib, bf16* __restrict__ wob,
    bf16* __restrict__ Xq, bf16* __restrict__ Xk, bf16* __restrict__ Xv)
{
    const size_t i = ((size_t)blockIdx.x * 256 + threadIdx.x) * 8;
    const size_t o1 = (size_t)3 * EMB * EMB;        //  3,145,728
    const size_t o2 = o1 + (size_t)EMB * EMB;       //  4,194,304
    const size_t o3 = o2 + (size_t)MROWS * EMB;     //  8,388,608
    const size_t o4 = o3 + (size_t)MROWS * EMB;     // 12,582,912
    const float* src; bf16* dst; size_t j;
    if      (i < o1) { src = w_in;  dst = wib; j = i; }
    else if (i < o2) { src = w_out; dst = wob; j = i - o1; }
    else if (i < o3) { src = q_in;  dst = Xq;  j = i - o2; }
    else if (i < o4) { src = k_in;  dst = Xk;  j = i - o3; }
    else             { src = v_in;  dst = Xv;  j = i - o4; }
    *reinterpret_cast<bf16x8*>(dst + j) = ld8_cvt(src + j);
}

// ---------------------------------------------------------------------------
// Fused QKV projection, 2-phase double-buffered GLL staging (round 7).
// V is written TRANSPOSED directly ([bh][d][s]) in the epilogue — the
// separate transpose_v kernel and its 32 MB Vh round-trip are deleted.
// Epilogue: Qh[bh][l][d] (x0.125*log2e), Kh[bh][s][d], Vt[bh][d][s].
// ---------------------------------------------------------------------------
__global__ __launch_bounds__(256) void qkv_gemm(
    const bf16* __restrict__ Xq, const bf16* __restrict__ Xk,
    const bf16* __restrict__ Xv, const bf16* __restrict__ wib,
    const float* __restrict__ b_in,
    bf16* __restrict__ Qh, bf16* __restrict__ Kh, bf16* __restrict__ Vt)
{
    __shared__ alignas(16) bf16 lds_a[2][128 * 32];
    __shared__ alignas(16) bf16 lds_b[2][128 * 32];

    const int tid  = threadIdx.x;
    const int lane = tid & 63;
    const int wv   = tid >> 6;
    const int quad = lane >> 4;
    const int lx   = lane & 15;

    const int m0  = blockIdx.x * 128;
    const int n0g = blockIdx.y * 128;
    const int chunk = n0g >> 10;              // 0=Q, 1=K, 2=V
    const bf16* Aop = (chunk == 0) ? Xq : (chunk == 1) ? Xk : Xv;

    const int wm = (wv >> 1) * 64;
    const int wn = (wv & 1) * 64;

    // GLL mapping: wave wv, issue i covers rows 16*wv + 64*i + (lane>>2)
    const int gr = 16 * wv + (lane >> 2);
    const int gc = (lane & 3) * 8;
    const bf16* gA = Aop + (size_t)(m0 + gr) * EMB + gc;
    const bf16* gB = wib + (size_t)(n0g + gr) * EMB + gc;
    bf16* lA = &lds_a[0][wv * 512];           // buf stride 4096 elems
    bf16* lB = &lds_b[0][wv * 512];
    const int BUF = 128 * 32;

    f32x4 acc[4][4];
#pragma unroll
    for (int i = 0; i < 4; i++)
#pragma unroll
        for (int j = 0; j < 4; j++) acc[i][j] = (f32x4){0.f, 0.f, 0.f, 0.f};

    // prologue: stage kt=0 into buf 0
    gll16(gA, lA);
    gll16(gA + 64 * EMB, lA + 2048);
    gll16(gB, lB);
    gll16(gB + 64 * EMB, lB + 2048);
    __syncthreads();   // vmcnt(0) drain: buf 0 ready

    int cur = 0;
    for (int kt = 0; kt < EMB; kt += 32) {
        // prefetch next K-slab into the other buffer (overlaps this compute)
        if (kt + 32 < EMB) {
            const int nx = cur ^ 1;
            gll16(gA + kt + 32, lA + nx * BUF);
            gll16(gA + 64 * EMB + kt + 32, lA + nx * BUF + 2048);
            gll16(gB + kt + 32, lB + nx * BUF);
            gll16(gB + 64 * EMB + kt + 32, lB + nx * BUF + 2048);
        }

        bf16x8 af[4], bfv[4];
        const int ka = quad * 8;
        const bf16* pa = &lds_a[cur][0];
        const bf16* pb = &lds_b[cur][0];
#pragma unroll
        for (int sm = 0; sm < 4; sm++)
            af[sm] = *reinterpret_cast<const bf16x8*>(pa + (wm + sm * 16 + lx) * 32 + ka);
#pragma unroll
        for (int sn = 0; sn < 4; sn++)
            bfv[sn] = *reinterpret_cast<const bf16x8*>(pb + (wn + sn * 16 + lx) * 32 + ka);
#pragma unroll
        for (int sm = 0; sm < 4; sm++)
#pragma unroll
            for (int sn = 0; sn < 4; sn++)
                acc[sm][sn] = mfma16(af[sm], bfv[sn], acc[sm][sn]);

        if (kt + 32 < EMB) __syncthreads();  // prefetch landed + all waves done reading buf[cur]
        cur ^= 1;
    }

    const float scale = (chunk == 0) ? 0.18033688011112042f : 1.0f;
    bf16* dst = (chunk == 0) ? Qh : (chunk == 1) ? Kh : Vt;
#pragma unroll
    for (int sn = 0; sn < 4; sn++) {
        const int n_g = n0g + wn + sn * 16 + lx;
        const float bias = b_in[n_g];
        const int nc = n_g & (EMB - 1);
        const int h  = nc >> 6;
        const int dd = nc & 63;
#pragma unroll
        for (int sm = 0; sm < 4; sm++) {
#pragma unroll
            for (int r = 0; r < 4; r++) {
                const int m_g = m0 + wm + sm * 16 + quad * 4 + r;  // row = l*B + b
                const int t = m_g >> 1;
                const int b = m_g & 1;
                const int bhidx = b * NH + h;
                const float v = (acc[sm][sn][r] + bias) * scale;
                const size_t off = (chunk == 2)
                    ? ((size_t)bhidx * HD + dd) * S_SEQ + t     // V transposed
                    : ((size_t)bhidx * S_SEQ + t) * HD + dd;    // Q, K row-major
                dst[off] = __float2bfloat16(v);
            }
        }
    }
}

// ---------------------------------------------------------------------------
// Flash attention: no-max log2-domain softmax, q=32/wave, K+V via
// global_load_lds pre-swizzled, double-buffered 64 KiB. P-pack via packbf2
// (verified; cvt_pk asm was wrong — round-9 lesson).
// ---------------------------------------------------------------------------
__global__ __launch_bounds__(256, 2) void attn_kernel(
    const bf16* __restrict__ Qh, const bf16* __restrict__ Kh,
    const bf16* __restrict__ Vt, bf16* __restrict__ ctx)
{
    __shared__ alignas(16) bf16 k_lds[2][128 * 64];  // [s][d], col^row swizzled
    __shared__ alignas(16) bf16 v_lds[2][64 * 128];  // [d][s], chunk^d swizzled

    const int tid  = threadIdx.x;
    const int lane = tid & 63;
    const int wv   = tid >> 6;      // 0..3
    const int quad = lane >> 4;
    const int lx   = lane & 15;
    const int lx7  = lane & 7;

    const int bh = blockIdx.y;
    const int l0 = blockIdx.x * 128;
    const int q0 = wv * 32;

    const bf16* Kbase = Kh + (size_t)bh * S_SEQ * HD;
    const bf16* Vbase = Vt + (size_t)bh * HD * S_SEQ;

    // Q as B-operand, two 16-q groups (a: rows q0.., b: rows q0+16..)
    const bf16* qrow = Qh + ((size_t)bh * L_SEQ + l0 + q0 + lx) * HD + quad * 8;
    const bf16x8 qa0 = *reinterpret_cast<const bf16x8*>(qrow);
    const bf16x8 qa1 = *reinterpret_cast<const bf16x8*>(qrow + 32);
    const bf16x8 qb0 = *reinterpret_cast<const bf16x8*>(qrow + 16 * HD);
    const bf16x8 qb1 = *reinterpret_cast<const bf16x8*>(qrow + 16 * HD + 32);

    f32x4 rva = (f32x4){0.f, 0.f, 0.f, 0.f};   // per-lane partial l sums
    f32x4 rvb = (f32x4){0.f, 0.f, 0.f, 0.f};
    f32x4 acca[4], accb[4];
#pragma unroll
    for (int sn = 0; sn < 4; sn++) {
        acca[sn] = (f32x4){0.f, 0.f, 0.f, 0.f};
        accb[sn] = (f32x4){0.f, 0.f, 0.f, 0.f};
    }

    // K staging: LDS row kr = tid>>3 (+32 per issue), chunk kj = tid&7;
    // source col pre-swizzled: LDS[r][j] = K[s0+r][(j ^ (r&7))*8..]
    const int kr = tid >> 3;
    const int kj = tid & 7;
    const bf16* gK = Kbase + (size_t)kr * HD + ((kj ^ (kr & 7)) << 3);
    // V staging: LDS d-row vd = tid>>4 (+16 per issue), chunk vj = tid&15;
    // LDS[d][j] = V[d][s0 + (j ^ (d&7))*8..]
    const int vd = tid >> 4;
    const int vj = tid & 15;
    const bf16* gV = Vbase + (size_t)vd * S_SEQ + ((vj ^ (vd & 7)) << 3);

    // wave-uniform LDS dest bases (elems); each issue covers +2048 elems
    bf16* kdst[2] = { &k_lds[0][wv * 512], &k_lds[1][wv * 512] };
    bf16* vdst[2] = { &v_lds[0][wv * 512], &v_lds[1][wv * 512] };

    // prologue: stage tile 0 into buf 0
#pragma unroll
    for (int i = 0; i < 4; i++) {
        gll16(gK + (size_t)(i * 32) * HD, kdst[0] + i * 2048);
        gll16(gV + (size_t)(i * 16) * S_SEQ, vdst[0] + i * 2048);
    }

    int cur = 0;
    for (int s0 = 0; s0 < S_SEQ; s0 += 128) {
        __syncthreads();   // vmcnt(0)+barrier: buf[cur] DMA complete, safe reuse

        if (s0 + 128 < S_SEQ) {
            bf16* kd = kdst[cur ^ 1];
            bf16* vdp = vdst[cur ^ 1];
#pragma unroll
            for (int i = 0; i < 4; i++) {
                gll16(gK + (size_t)(s0 + 128 + i * 32) * HD, kd + i * 2048);
                gll16(gV + (size_t)(i * 16) * S_SEQ + s0 + 128, vdp + i * 2048);
            }
        }
        const bf16* kb = &k_lds[cur][0];
        const bf16* vb = &v_lds[cur][0];

        // QK^T both groups: one K-frag read feeds 4 mfmas
        f32x4 sa[8], sb[8];
#pragma unroll
        for (int c = 0; c < 8; c++) {
            const bf16* krp = kb + (c * 16 + lx) * 64;
            bf16x8 kf0 = *reinterpret_cast<const bf16x8*>(krp + ((quad ^ lx7) << 3));
            bf16x8 kf1 = *reinterpret_cast<const bf16x8*>(krp + (((quad + 4) ^ lx7) << 3));
            f32x4 t0 = (f32x4){0.f, 0.f, 0.f, 0.f};
            t0 = mfma16(kf0, qa0, t0);
            t0 = mfma16(kf1, qa1, t0);
            sa[c] = t0;
            f32x4 t1 = (f32x4){0.f, 0.f, 0.f, 0.f};
            t1 = mfma16(kf0, qb0, t1);
            t1 = mfma16(kf1, qb1, t1);
            sb[c] = t1;
        }

        // P = exp2(s) directly (no max); accumulate l per-lane; pack for PV.
        uint32_t pka0[8], pka1[8], pkb0[8], pkb1[8];
#pragma unroll
        for (int c = 0; c < 8; c++) {
#pragma unroll
            for (int r = 0; r < 4; r++) sa[c][r] = __builtin_amdgcn_exp2f(sa[c][r]);
            rva += sa[c];
            pka0[c] = packbf2(sa[c][0], sa[c][1]);
            pka1[c] = packbf2(sa[c][2], sa[c][3]);
        }
#pragma unroll
        for (int c = 0; c < 8; c++) {
#pragma unroll
            for (int r = 0; r < 4; r++) sb[c][r] = __builtin_amdgcn_exp2f(sb[c][r]);
            rvb += sb[c];
            pkb0[c] = packbf2(sb[c][0], sb[c][1]);
            pkb1[c] = packbf2(sb[c][2], sb[c][3]);
        }

        // PV: each V-frag read feeds both groups' mfmas
#pragma unroll
        for (int sk = 0; sk < 4; sk++) {
            const bf16x8 pfa = pfrag(pka0, pka1, sk);
            const bf16x8 pfb = pfrag(pkb0, pkb1, sk);
#pragma unroll
            for (int sn = 0; sn < 4; sn++) {
                const bf16x8 vf = *reinterpret_cast<const bf16x8*>(
                    vb + (sn * 16 + lx) * 128 + (((sk * 4 + quad) ^ lx7) << 3));
                acca[sn] = mfma16(pfa, vf, acca[sn]);
                accb[sn] = mfma16(pfb, vf, accb[sn]);
            }
        }
        cur ^= 1;
    }

    // epilogue: single cross-lane l reduce
    float la = (rva[0] + rva[1]) + (rva[2] + rva[3]);
    la += __shfl_xor(la, 16);
    la += __shfl_xor(la, 32);
    float lbs = (rvb[0] + rvb[1]) + (rvb[2] + rvb[3]);
    lbs += __shfl_xor(lbs, 16);
    lbs += __shfl_xor(lbs, 32);

    const int b = bh >> 4;
    const int h = bh & 15;
#pragma unroll
    for (int r = 0; r < 4; r++) {
        const float lra = __shfl(la, quad * 20 + r);
        const float lrb = __shfl(lbs, quad * 20 + r);
        const float inva = 1.f / lra;
        const float invb = 1.f / lrb;
        const int lA = l0 + q0 + quad * 4 + r;
        const int lB = lA + 16;
#pragma unroll
        for (int sn = 0; sn < 4; sn++) {
            const int dd = sn * 16 + lx;
            ctx[(size_t)(lA * BATCH + b) * EMB + h * HD + dd] =
                __float2bfloat16(acca[sn][r] * inva);
            ctx[(size_t)(lB * BATCH + b) * EMB + h * HD + dd] =
                __float2bfloat16(accb[sn][r] * invb);
        }
    }
}

// ---------------------------------------------------------------------------
// Output projection: 64x128 tile -> 512 blocks (2/CU), 2-phase double-buffered
// GLL staging. LDS 24 KiB. fp32 out.
// ---------------------------------------------------------------------------
__global__ __launch_bounds__(256) void out_gemm(
    const bf16* __restrict__ ctx, const bf16* __restrict__ wob,
    const float* __restrict__ b_out, float* __restrict__ out)
{
    __shared__ alignas(16) bf16 lds_a[2][64 * 32];
    __shared__ alignas(16) bf16 lds_b[2][128 * 32];

    const int tid  = threadIdx.x;
    const int lane = tid & 63;
    const int wv   = tid >> 6;
    const int quad = lane >> 4;
    const int lx   = lane & 15;

    const int m0 = blockIdx.x * 64;
    const int n0 = blockIdx.y * 128;

    const int wm = (wv >> 1) * 32;
    const int wn = (wv & 1) * 64;

    const int gr = 16 * wv + (lane >> 2);
    const int gc = (lane & 3) * 8;
    const bf16* gA = ctx + (size_t)(m0 + gr) * EMB + gc;   // rows 0..63
    const bf16* gB = wob + (size_t)(n0 + gr) * EMB + gc;   // rows 0..63 (+64)
    bf16* lA = &lds_a[0][wv * 512];
    bf16* lB = &lds_b[0][wv * 512];
    const int BUFA = 64 * 32;
    const int BUFB = 128 * 32;

    f32x4 acc[2][4];
#pragma unroll
    for (int i = 0; i < 2; i++)
#pragma unroll
        for (int j = 0; j < 4; j++) acc[i][j] = (f32x4){0.f, 0.f, 0.f, 0.f};

    // prologue: stage kt=0 into buf 0
    gll16(gA, lA);
    gll16(gB, lB);
    gll16(gB + 64 * EMB, lB + 2048);
    __syncthreads();

    int cur = 0;
    for (int kt = 0; kt < EMB; kt += 32) {
        if (kt + 32 < EMB) {
            const int nx = cur ^ 1;
            gll16(gA + kt + 32, lA + nx * BUFA);
            gll16(gB + kt + 32, lB + nx * BUFB);
            gll16(gB + 64 * EMB + kt + 32, lB + nx * BUFB + 2048);
        }

        bf16x8 af[2], bfv[4];
        const int ka = quad * 8;
        const bf16* pa = &lds_a[cur][0];
        const bf16* pb = &lds_b[cur][0];
#pragma unroll
        for (int sm = 0; sm < 2; sm++)
            af[sm] = *reinterpret_cast<const bf16x8*>(pa + (wm + sm * 16 + lx) * 32 + ka);
#pragma unroll
        for (int sn = 0; sn < 4; sn++)
            bfv[sn] = *reinterpret_cast<const bf16x8*>(pb + (wn + sn * 16 + lx) * 32 + ka);
#pragma unroll
        for (int sm = 0; sm < 2; sm++)
#pragma unroll
            for (int sn = 0; sn < 4; sn++)
                acc[sm][sn] = mfma16(af[sm], bfv[sn], acc[sm][sn]);

        if (kt + 32 < EMB) __syncthreads();
        cur ^= 1;
    }

#pragma unroll
    for (int sn = 0; sn < 4; sn++) {
        const int n_g = n0 + wn + sn * 16 + lx;
        const float bias = b_out[n_g];
#pragma unroll
        for (int sm = 0; sm < 2; sm++) {
#pragma unroll
            for (int r = 0; r < 4; r++) {
                const int m_g = m0 + wm + sm * 16 + quad * 4 + r;
                out[(size_t)m_g * EMB + n_g] = acc[sm][sn][r] + bias;
            }
        }
    }
}

extern "C" void kernel_launch(void* const* d_in, const int* in_sizes, int n_in,
                              void* d_out, int out_size, void* d_ws, size_t ws_size,
                              hipStream_t stream)
{
    const float* query = (const float*)d_in[0];
    const float* key_  = (const float*)d_in[1];
    const float* value = (const float*)d_in[2];
    const float* w_in  = (const float*)d_in[3];
    const float* b_in  = (const float*)d_in[4];
    const float* w_out = (const float*)d_in[5];
    const float* b_out = (const float*)d_in[6];
    float* out = (float*)d_out;

    const size_t seg = (size_t)MROWS * EMB;      // 4,194,304 elems (8 MiB bf16)
    bf16* wib = (bf16*)d_ws;                     // 3*EMB*EMB
    bf16* wob = wib + (size_t)3 * EMB * EMB;     // EMB*EMB
    bf16* Xq  = wob + (size_t)EMB * EMB;         // [m][k] bf16 inputs
    bf16* Xk  = Xq + seg;
    bf16* Xv  = Xk + seg;
    bf16* Qh  = Xv + seg;                        // [bh][l][d], scaled log2e/8
    bf16* Kh  = Qh + seg;                        // [bh][s][d]
    bf16* Vt  = Kh + seg;                        // [bh][d][s] — written directly by qkv_gemm
    bf16* ctx = Xq;                              // alias: Xq dead after qkv_gemm

    cvt_kernel<<<8192, 256, 0, stream>>>(w_in, w_out, query, key_, value,
                                         wib, wob, Xq, Xk, Xv);
    qkv_gemm<<<dim3(32, 24), 256, 0, stream>>>(Xq, Xk, Xv, wib, b_in, Qh, Kh, Vt);
    attn_kernel<<<dim3(16, 32), 256, 0, stream>>>(Qh, Kh, Vt, ctx);
    out_gemm<<<dim3(64, 8), 256, 0, stream>>>(ctx, wob, b_out, out);
}